// Round 4
// baseline (122.484 us; speedup 1.0000x reference)
//
#include <hip/hip_runtime.h>
#include <hip/hip_bf16.h>

// Problem: B=128, M=256, T=512, N=512
// attn[b,0,n] = softmax_n( sum_k tanh(g[b,k] + sum_t X[b,t,n]*We2[t,k]) * v[k] )
// g[b,k] = (concat(hidden,cell)[b] @ We1)[k] + be1[k] + be2[k]   (bv cancels in softmax)

typedef _Float16 half8 __attribute__((ext_vector_type(8)));
typedef float floatx4 __attribute__((ext_vector_type(4)));

__device__ __forceinline__ float fast_tanh(float x) {
    float cx = fminf(15.0f, fmaxf(-15.0f, x));
    float e = __expf(2.0f * cx);
    return (e - 1.0f) * __fdividef(1.0f, e + 1.0f);
}

// ---------------- K0: Af slabs, chunk u = ts*32 + c holds A[k=c*16+(l&15)]
// [t = ts*32 + (l>>4)*8 + j]  (A = We2^T, f16; 16B per (u,lane)) ----------------
__global__ __launch_bounds__(256) void k_prep_a(const float* __restrict__ We2,
                                                _Float16* __restrict__ Af) {
    __shared__ float w2[32][512];
    const int ts = blockIdx.x;            // 16 blocks, t-range 32 each
    for (int idx = threadIdx.x; idx < 32 * 512; idx += 256) {
        int tl = idx >> 9, k = idx & 511;
        w2[tl][k] = We2[(ts * 32 + tl) * 512 + k];     // coalesced
    }
    __syncthreads();
    for (int item = threadIdx.x; item < 32 * 64; item += 256) {
        int c = item >> 6, l = item & 63;              // c = chunk in slab
        int k  = c * 16 + (l & 15);
        int tl = (l >> 4) * 8;
        half8 h;
#pragma unroll
        for (int j = 0; j < 8; ++j) h[j] = (_Float16)w2[tl + j][k];
        *(half8*)&Af[(((size_t)ts * 32 + c) * 64 + l) * 8] = h;   // coalesced
    }
}

// ---------------- K1: g[b][k] = hc@We1 + be1 + be2 ----------------
__global__ __launch_bounds__(256) void k_hs(const float* __restrict__ hidden,
                                            const float* __restrict__ cell,
                                            const float* __restrict__ We1,
                                            const float* __restrict__ be1,
                                            const float* __restrict__ be2,
                                            float* __restrict__ g) {
    __shared__ __align__(16) float hcl[8][512];
    __shared__ float red[4][8][64];
    const int b0 = (blockIdx.x >> 3) << 3;
    const int k0 = (blockIdx.x & 7) << 6;
    for (int idx = threadIdx.x; idx < 8 * 512; idx += 256) {
        int bi = idx >> 9, j = idx & 511;
        hcl[bi][j] = (j < 256) ? hidden[(b0 + bi) * 256 + j]
                               : cell[(b0 + bi) * 256 + j - 256];
    }
    __syncthreads();
    const int kl = threadIdx.x & 63;
    const int jc = threadIdx.x >> 6;
    const int k  = k0 + kl;
    float acc[8] = {};
    for (int j = jc * 128; j < jc * 128 + 128; j += 4) {
        float w0 = We1[(j + 0) * 512 + k];
        float w1 = We1[(j + 1) * 512 + k];
        float w2 = We1[(j + 2) * 512 + k];
        float w3 = We1[(j + 3) * 512 + k];
#pragma unroll
        for (int bi = 0; bi < 8; ++bi) {
            float4 h = *(const float4*)&hcl[bi][j];
            acc[bi] += h.x * w0 + h.y * w1 + h.z * w2 + h.w * w3;
        }
    }
#pragma unroll
    for (int bi = 0; bi < 8; ++bi) red[jc][bi][kl] = acc[bi];
    __syncthreads();
    for (int idx = threadIdx.x; idx < 512; idx += 256) {
        int bi = idx >> 6, kk = idx & 63;
        float s = red[0][bi][kk] + red[1][bi][kk] + red[2][bi][kk] + red[3][bi][kk];
        int kg = k0 + kk;
        g[(b0 + bi) * 512 + kg] = s + be1[kg] + be2[kg];
    }
}

// ---------------- K2: fused GEMM + tanh + v-dot -> e[b][n] ----------------
// grid = 128 b * 16 nblocks(32).  256 threads = 4 waves; wave wv owns k
// [wv*128, wv*128+128) (8 kf) x 32 n (2 nf) -> 16 MFMA / t-step, B-frag
// reused 8x.  LDS: X strip [32 n][512 t] f16 = 32 KiB staged ONCE; main loop
// is BARRIER-FREE (A-frags stream from L2-hot Af, 1 KB coalesced per
// wave-load) with explicit 2-set register ping-pong prefetch.
__global__ __launch_bounds__(256, 3) void k_main(const float* __restrict__ X,
                                                 const _Float16* __restrict__ Af,
                                                 const float* __restrict__ g,
                                                 const float* __restrict__ vvec,
                                                 float* __restrict__ E) {
    __shared__ __align__(16) _Float16 XT[32 * 512];   // 32 KiB
    const int b    = blockIdx.x >> 4;
    const int n0   = (blockIdx.x & 15) << 5;
    const int tid  = threadIdx.x;
    const int lane = tid & 63;
    const int wv   = tid >> 6;        // 0..3
    const int l16  = lane & 15;
    const int lhi  = lane >> 4;       // 0..3

    // ---- stage X strip: coalesced f32 reads, f16 pack, swizzled b128 writes
    {
        const float* Xb = X + (size_t)b * (512 * 512) + n0;
        const int nl = tid & 31;
        const int tg = tid >> 5;       // 0..7
#pragma unroll 2
        for (int oct = 0; oct < 8; ++oct) {
            int t0 = tg * 64 + oct * 8;
            float f[8];
#pragma unroll
            for (int j = 0; j < 8; ++j) f[j] = Xb[(size_t)(t0 + j) * 512 + nl];
            half8 h;
#pragma unroll
            for (int j = 0; j < 8; ++j) h[j] = (_Float16)f[j];
            *(half8*)&XT[nl * 512 + (t0 ^ ((nl & 7) << 3))] = h;
        }
    }
    __syncthreads();   // the only barrier before the epilogue

    floatx4 acc[8][2];
#pragma unroll
    for (int a = 0; a < 8; ++a) {
        acc[a][0] = (floatx4){0.f, 0.f, 0.f, 0.f};
        acc[a][1] = (floatx4){0.f, 0.f, 0.f, 0.f};
    }

    // A chunk (wv,kf,ts) at element offset ts*16384 + (wv*8+kf)*512 + lane*8
    const _Float16* __restrict__ Ap = Af + (size_t)wv * 4096 + (size_t)lane * 8;
    const int bsw0 = ((0 * 16 + l16) & 7) << 3;      // swizzle masks for nf=0,1
    const int bsw1 = ((1 * 16 + l16) & 7) << 3;      // (equal, but keep explicit)
    const int brow0 = (0 * 16 + l16) * 512;
    const int brow1 = (1 * 16 + l16) * 512;

    half8 aA[8], aB[8], bA[2], bB[2];
    // prime ts = 0 into A-set
#pragma unroll
    for (int kf = 0; kf < 8; ++kf) aA[kf] = *(const half8*)&Ap[(size_t)kf * 512];
    {
        int t0 = lhi * 8;
        bA[0] = *(const half8*)&XT[brow0 + (t0 ^ bsw0)];
        bA[1] = *(const half8*)&XT[brow1 + (t0 ^ bsw1)];
    }

#pragma unroll
    for (int tp = 0; tp < 8; ++tp) {
        const int ts0 = tp * 2;
        // prefetch ts0+1 -> B set
        {
            const size_t ao = (size_t)(ts0 + 1) * 16384;
#pragma unroll
            for (int kf = 0; kf < 8; ++kf)
                aB[kf] = *(const half8*)&Ap[ao + (size_t)kf * 512];
            int t0 = (ts0 + 1) * 32 + lhi * 8;
            bB[0] = *(const half8*)&XT[brow0 + (t0 ^ bsw0)];
            bB[1] = *(const half8*)&XT[brow1 + (t0 ^ bsw1)];
        }
        // MFMA with A set (tile ts0)
#pragma unroll
        for (int kf = 0; kf < 8; ++kf) {
            acc[kf][0] = __builtin_amdgcn_mfma_f32_16x16x32_f16(aA[kf], bA[0], acc[kf][0], 0, 0, 0);
            acc[kf][1] = __builtin_amdgcn_mfma_f32_16x16x32_f16(aA[kf], bA[1], acc[kf][1], 0, 0, 0);
        }
        // prefetch ts0+2 -> A set (clamped; tp=7 extra loads are dead)
        if (tp < 7) {
            const size_t ao = (size_t)(ts0 + 2) * 16384;
#pragma unroll
            for (int kf = 0; kf < 8; ++kf)
                aA[kf] = *(const half8*)&Ap[ao + (size_t)kf * 512];
            int t0 = (ts0 + 2) * 32 + lhi * 8;
            bA[0] = *(const half8*)&XT[brow0 + (t0 ^ bsw0)];
            bA[1] = *(const half8*)&XT[brow1 + (t0 ^ bsw1)];
        }
        // MFMA with B set (tile ts0+1)
#pragma unroll
        for (int kf = 0; kf < 8; ++kf) {
            acc[kf][0] = __builtin_amdgcn_mfma_f32_16x16x32_f16(aB[kf], bB[0], acc[kf][0], 0, 0, 0);
            acc[kf][1] = __builtin_amdgcn_mfma_f32_16x16x32_f16(aB[kf], bB[1], acc[kf][1], 0, 0, 0);
        }
    }

    // ---- fused epilogue: s[n] = sum_k tanh(acc + g[k]) * v[k]
    // C/D layout (16x16x32): col n = lane&15, row k = (lane>>4)*4 + reg
    const float* gb = g + b * 512;
    float s0 = 0.f, s1 = 0.f;
#pragma unroll
    for (int kf = 0; kf < 8; ++kf) {
        const int kb = wv * 128 + kf * 16 + lhi * 4;
        float g0 = gb[kb + 0], g1 = gb[kb + 1], g2 = gb[kb + 2], g3 = gb[kb + 3];
        float v0 = vvec[kb + 0], v1 = vvec[kb + 1], v2 = vvec[kb + 2], v3 = vvec[kb + 3];
        s0 += fast_tanh(acc[kf][0][0] + g0) * v0;
        s0 += fast_tanh(acc[kf][0][1] + g1) * v1;
        s0 += fast_tanh(acc[kf][0][2] + g2) * v2;
        s0 += fast_tanh(acc[kf][0][3] + g3) * v3;
        s1 += fast_tanh(acc[kf][1][0] + g0) * v0;
        s1 += fast_tanh(acc[kf][1][1] + g1) * v1;
        s1 += fast_tanh(acc[kf][1][2] + g2) * v2;
        s1 += fast_tanh(acc[kf][1][3] + g3) * v3;
    }
    s0 += __shfl_xor(s0, 16);  s0 += __shfl_xor(s0, 32);
    s1 += __shfl_xor(s1, 16);  s1 += __shfl_xor(s1, 32);

    __syncthreads();               // all XT reads done -> reuse LDS
    float* ered = (float*)XT;      // [4 waves][32 n] overlay
    if (lane < 16) {
        ered[wv * 32 + l16]      = s0;
        ered[wv * 32 + 16 + l16] = s1;
    }
    __syncthreads();
    if (tid < 32) {
        float e = ered[tid] + ered[32 + tid] + ered[64 + tid] + ered[96 + tid];
        E[b * 512 + n0 + tid] = e;
    }
}

// ---------------- K3: softmax over n (512) per batch row ----------------
__global__ __launch_bounds__(256) void k_softmax(const float* __restrict__ E,
                                                 float* __restrict__ out) {
    __shared__ float rmax[4], rsum[4];
    const int b = blockIdx.x;
    const int tid = threadIdx.x;
    float e0 = E[b * 512 + tid];
    float e1 = E[b * 512 + 256 + tid];
    float m = fmaxf(e0, e1);
    for (int o = 32; o > 0; o >>= 1) m = fmaxf(m, __shfl_xor(m, o));
    if ((tid & 63) == 0) rmax[tid >> 6] = m;
    __syncthreads();
    m = fmaxf(fmaxf(rmax[0], rmax[1]), fmaxf(rmax[2], rmax[3]));
    float p0 = __expf(e0 - m), p1 = __expf(e1 - m);
    float ss = p0 + p1;
    for (int o = 32; o > 0; o >>= 1) ss += __shfl_xor(ss, o);
    if ((tid & 63) == 0) rsum[tid >> 6] = ss;
    __syncthreads();
    ss = rsum[0] + rsum[1] + rsum[2] + rsum[3];
    float inv = __fdividef(1.0f, ss);
    out[b * 512 + tid] = p0 * inv;
    out[b * 512 + 256 + tid] = p1 * inv;
}

extern "C" void kernel_launch(void* const* d_in, const int* in_sizes, int n_in,
                              void* d_out, int out_size, void* d_ws, size_t ws_size,
                              hipStream_t stream) {
    const float* hidden = (const float*)d_in[0];
    const float* cell   = (const float*)d_in[1];
    const float* X      = (const float*)d_in[2];
    const float* We1    = (const float*)d_in[3];
    const float* be1    = (const float*)d_in[4];
    const float* We2    = (const float*)d_in[5];
    const float* be2    = (const float*)d_in[6];
    const float* v      = (const float*)d_in[7];
    float* out = (float*)d_out;

    char* ws = (char*)d_ws;
    _Float16* Af = (_Float16*)ws;                        // 512*512*2  = 524288 B
    float* g     = (float*)(ws + 524288);                // 128*512*4  = 262144 B
    float* E     = (float*)(ws + 524288 + 262144);       // 128*512*4  = 262144 B

    k_prep_a<<<16, 256, 0, stream>>>(We2, Af);
    k_hs<<<128, 256, 0, stream>>>(hidden, cell, We1, be1, be2, g);
    k_main<<<2048, 256, 0, stream>>>(X, Af, g, v, E);
    k_softmax<<<128, 256, 0, stream>>>(E, out);
}

// Round 5
// 83.007 us; speedup vs baseline: 1.4756x; 1.4756x over previous
//
#include <hip/hip_runtime.h>
#include <hip/hip_bf16.h>

// Problem: B=128, M=256, T=512, N=512
// attn[b,0,n] = softmax_n( sum_k tanh(g[b,k] + sum_t X[b,t,n]*We2[t,k]) * v[k] )
// g[b,k] = (concat(hidden,cell)[b] @ We1)[k] + be1[k] + be2[k]   (bv cancels in softmax)

typedef _Float16 half8 __attribute__((ext_vector_type(8)));
typedef float floatx4 __attribute__((ext_vector_type(4)));

// async global->LDS DMA, 16B per lane; LDS dest = wave-uniform base + lane*16
#define GLOAD_LDS16(gp, lp) __builtin_amdgcn_global_load_lds(                  \
    (const __attribute__((address_space(1))) void*)(const void*)(gp),          \
    (__attribute__((address_space(3))) void*)(void*)(lp), 16, 0, 0)

__device__ __forceinline__ float fast_tanh(float x) {
    float cx = fminf(15.0f, fmaxf(-15.0f, x));
    float e = __expf(2.0f * cx);
    return (e - 1.0f) * __fdividef(1.0f, e + 1.0f);
}

// ---------------- K0: Af slabs, per ts (32 t): chunk c = k-16-group 0..31,
// lane l: holds A[k=c*16+(l&15)][t=ts*32+(l>>4)*8+j], j=0..7 (A=We2^T, f16).
// Element offset: ts*16384 + c*512 + l*8.  Frag-linear => gload_lds-ready.
__global__ __launch_bounds__(256) void k_prep_a(const float* __restrict__ We2,
                                                _Float16* __restrict__ Af) {
    __shared__ float w2[32][512];
    const int ts = blockIdx.x;            // 16 blocks, t-range 32 each
    for (int idx = threadIdx.x; idx < 32 * 512; idx += 256) {
        int tl = idx >> 9, k = idx & 511;
        w2[tl][k] = We2[(ts * 32 + tl) * 512 + k];     // coalesced
    }
    __syncthreads();
    for (int item = threadIdx.x; item < 32 * 64; item += 256) {
        int c = item >> 6, l = item & 63;
        int k  = c * 16 + (l & 15);
        int tl = (l >> 4) * 8;
        half8 h;
#pragma unroll
        for (int j = 0; j < 8; ++j) h[j] = (_Float16)w2[tl + j][k];
        *(half8*)&Af[(((size_t)ts * 32 + c) * 64 + l) * 8] = h;   // coalesced
    }
}

// ---------------- K1: g[b][k] = hc@We1 + be1 + be2 ----------------
__global__ __launch_bounds__(256) void k_hs(const float* __restrict__ hidden,
                                            const float* __restrict__ cell,
                                            const float* __restrict__ We1,
                                            const float* __restrict__ be1,
                                            const float* __restrict__ be2,
                                            float* __restrict__ g) {
    __shared__ __align__(16) float hcl[8][512];
    __shared__ float red[4][8][64];
    const int b0 = (blockIdx.x >> 3) << 3;
    const int k0 = (blockIdx.x & 7) << 6;
    for (int idx = threadIdx.x; idx < 8 * 512; idx += 256) {
        int bi = idx >> 9, j = idx & 511;
        hcl[bi][j] = (j < 256) ? hidden[(b0 + bi) * 256 + j]
                               : cell[(b0 + bi) * 256 + j - 256];
    }
    __syncthreads();
    const int kl = threadIdx.x & 63;
    const int jc = threadIdx.x >> 6;
    const int k  = k0 + kl;
    float acc[8] = {};
    for (int j = jc * 128; j < jc * 128 + 128; j += 4) {
        float w0 = We1[(j + 0) * 512 + k];
        float w1 = We1[(j + 1) * 512 + k];
        float w2 = We1[(j + 2) * 512 + k];
        float w3 = We1[(j + 3) * 512 + k];
#pragma unroll
        for (int bi = 0; bi < 8; ++bi) {
            float4 h = *(const float4*)&hcl[bi][j];
            acc[bi] += h.x * w0 + h.y * w1 + h.z * w2 + h.w * w3;
        }
    }
#pragma unroll
    for (int bi = 0; bi < 8; ++bi) red[jc][bi][kl] = acc[bi];
    __syncthreads();
    for (int idx = threadIdx.x; idx < 512; idx += 256) {
        int bi = idx >> 6, kk = idx & 63;
        float s = red[0][bi][kk] + red[1][bi][kk] + red[2][bi][kk] + red[3][bi][kk];
        int kg = k0 + kk;
        g[(b0 + bi) * 512 + kg] = s + be1[kg] + be2[kg];
    }
}

// ---------------- K2: fused GEMM + tanh + v-dot -> e[b][n] ----------------
// grid = 128 b * 8 nblocks(64).  512 threads = 8 waves; wave wv owns
// k [wv*64, wv*64+64) (4 kf) x n 64 (4 nf) -> 16 MFMA / ts-step.
// LDS dbuf: A slab [512k][32t] f16 32KB via global_load_lds (DMA, no VGPRs,
// compiler can't sink it); X chunk [64n][32t] f16 4KB reg-staged (T14 split:
// loads issued before MFMA cluster, ds_write after).  All LDS access
// frag-linear stride-16B => conflict-free, no swizzle (rule #21: linear
// source + linear dest + linear read).  73.7KB LDS -> 2 blocks/CU.
__global__ __launch_bounds__(512, 4) void k_main(const float* __restrict__ X,
                                                 const _Float16* __restrict__ Af,
                                                 const float* __restrict__ g,
                                                 const float* __restrict__ vvec,
                                                 float* __restrict__ E) {
    __shared__ __align__(16) _Float16 Ab[2][16384];   // 2 x 32 KiB
    __shared__ __align__(16) _Float16 Xb[2][2048];    // 2 x 4 KiB
    const int b    = blockIdx.x >> 3;
    const int n0   = (blockIdx.x & 7) << 6;
    const int tid  = threadIdx.x;
    const int lane = tid & 63;
    const int wv   = tid >> 6;        // 0..7
    const int l16  = lane & 15;
    const int lhi  = lane >> 4;       // 0..3

    const float* Xg = X + (size_t)b * (512 * 512) + n0;
    // X staging role: threads 0..255, thread -> (n = tid&63, oct = (tid>>6)&3)
    const int  xn    = tid & 63;
    const int  xo    = (tid >> 6) & 3;
    const bool xact  = (tid < 256);
    const int  xslot = ((xn >> 4) * 64 + xo * 16 + (xn & 15)) * 8;  // elem ofs
    // A staging: wave wv covers chunk region [wv*2048, wv*2048+2048) elems
    const _Float16* AgW = Af + (size_t)wv * 2048 + (size_t)lane * 8;

    // ---- prologue: stage ts = 0
    {
#pragma unroll
        for (int i = 0; i < 4; ++i)
            GLOAD_LDS16(AgW + i * 512, &Ab[0][wv * 2048 + i * 512 + lane * 8]);
        if (xact) {
            float f[8];
#pragma unroll
            for (int j = 0; j < 8; ++j) f[j] = Xg[(size_t)(xo * 8 + j) * 512 + xn];
            half8 h;
#pragma unroll
            for (int j = 0; j < 8; ++j) h[j] = (_Float16)f[j];
            *(half8*)&Xb[0][xslot] = h;
        }
    }
    __syncthreads();

    floatx4 acc[4][4];
#pragma unroll
    for (int a = 0; a < 4; ++a)
#pragma unroll
        for (int c = 0; c < 4; ++c) acc[a][c] = (floatx4){0.f, 0.f, 0.f, 0.f};

    float xf[8];
    for (int ts = 0; ts < 16; ++ts) {
        const int cur = ts & 1;
        const int nxt = cur ^ 1;
        // ---- issue next-tile staging EARLY (DMA + reg loads), before MFMAs
        if (ts < 15) {
#pragma unroll
            for (int i = 0; i < 4; ++i)
                GLOAD_LDS16(AgW + (size_t)(ts + 1) * 16384 + i * 512,
                            &Ab[nxt][wv * 2048 + i * 512 + lane * 8]);
            if (xact) {
#pragma unroll
                for (int j = 0; j < 8; ++j)
                    xf[j] = Xg[(size_t)((ts + 1) * 32 + xo * 8 + j) * 512 + xn];
            }
        }
        // ---- compute current tile: 8 conflict-free ds_read_b128 + 16 MFMA
        {
            half8 af0 = *(const half8*)&Ab[cur][(wv * 4 + 0) * 512 + lane * 8];
            half8 af1 = *(const half8*)&Ab[cur][(wv * 4 + 1) * 512 + lane * 8];
            half8 af2 = *(const half8*)&Ab[cur][(wv * 4 + 2) * 512 + lane * 8];
            half8 af3 = *(const half8*)&Ab[cur][(wv * 4 + 3) * 512 + lane * 8];
#pragma unroll
            for (int nf = 0; nf < 4; ++nf) {
                half8 bf = *(const half8*)&Xb[cur][(nf * 64 + lane) * 8];
                acc[0][nf] = __builtin_amdgcn_mfma_f32_16x16x32_f16(af0, bf, acc[0][nf], 0, 0, 0);
                acc[1][nf] = __builtin_amdgcn_mfma_f32_16x16x32_f16(af1, bf, acc[1][nf], 0, 0, 0);
                acc[2][nf] = __builtin_amdgcn_mfma_f32_16x16x32_f16(af2, bf, acc[2][nf], 0, 0, 0);
                acc[3][nf] = __builtin_amdgcn_mfma_f32_16x16x32_f16(af3, bf, acc[3][nf], 0, 0, 0);
            }
        }
        // ---- late X write into the next buffer (T14), then barrier
        if (ts < 15 && xact) {
            half8 h;
#pragma unroll
            for (int j = 0; j < 8; ++j) h[j] = (_Float16)xf[j];
            *(half8*)&Xb[nxt][xslot] = h;
        }
        __syncthreads();
    }

    // ---- fused epilogue: s[n] = sum_k tanh(acc + g[k]) * v[k]
    // C/D layout (16x16x32): col n = lane&15, row k = (lane>>4)*4 + reg
    const float* gb = g + b * 512;
    float s[4] = {0.f, 0.f, 0.f, 0.f};
#pragma unroll
    for (int kf = 0; kf < 4; ++kf) {
        const int kb = wv * 64 + kf * 16 + lhi * 4;
        float g0 = gb[kb + 0], g1 = gb[kb + 1], g2 = gb[kb + 2], g3 = gb[kb + 3];
        float v0 = vvec[kb + 0], v1 = vvec[kb + 1], v2 = vvec[kb + 2], v3 = vvec[kb + 3];
#pragma unroll
        for (int nf = 0; nf < 4; ++nf) {
            s[nf] += fast_tanh(acc[kf][nf][0] + g0) * v0;
            s[nf] += fast_tanh(acc[kf][nf][1] + g1) * v1;
            s[nf] += fast_tanh(acc[kf][nf][2] + g2) * v2;
            s[nf] += fast_tanh(acc[kf][nf][3] + g3) * v3;
        }
    }
#pragma unroll
    for (int nf = 0; nf < 4; ++nf) {
        s[nf] += __shfl_xor(s[nf], 16);
        s[nf] += __shfl_xor(s[nf], 32);
    }
    __syncthreads();               // all LDS reads done -> reuse as overlay
    float* ered = (float*)&Ab[0][0];      // [8 waves][64 n]
    if (lane < 16) {
#pragma unroll
        for (int nf = 0; nf < 4; ++nf) ered[wv * 64 + nf * 16 + l16] = s[nf];
    }
    __syncthreads();
    if (tid < 64) {
        float e = 0.f;
#pragma unroll
        for (int w = 0; w < 8; ++w) e += ered[w * 64 + tid];
        E[b * 512 + n0 + tid] = e;
    }
}

// ---------------- K3: softmax over n (512) per batch row ----------------
__global__ __launch_bounds__(256) void k_softmax(const float* __restrict__ E,
                                                 float* __restrict__ out) {
    __shared__ float rmax[4], rsum[4];
    const int b = blockIdx.x;
    const int tid = threadIdx.x;
    float e0 = E[b * 512 + tid];
    float e1 = E[b * 512 + 256 + tid];
    float m = fmaxf(e0, e1);
    for (int o = 32; o > 0; o >>= 1) m = fmaxf(m, __shfl_xor(m, o));
    if ((tid & 63) == 0) rmax[tid >> 6] = m;
    __syncthreads();
    m = fmaxf(fmaxf(rmax[0], rmax[1]), fmaxf(rmax[2], rmax[3]));
    float p0 = __expf(e0 - m), p1 = __expf(e1 - m);
    float ss = p0 + p1;
    for (int o = 32; o > 0; o >>= 1) ss += __shfl_xor(ss, o);
    if ((tid & 63) == 0) rsum[tid >> 6] = ss;
    __syncthreads();
    ss = rsum[0] + rsum[1] + rsum[2] + rsum[3];
    float inv = __fdividef(1.0f, ss);
    out[b * 512 + tid] = p0 * inv;
    out[b * 512 + 256 + tid] = p1 * inv;
}

extern "C" void kernel_launch(void* const* d_in, const int* in_sizes, int n_in,
                              void* d_out, int out_size, void* d_ws, size_t ws_size,
                              hipStream_t stream) {
    const float* hidden = (const float*)d_in[0];
    const float* cell   = (const float*)d_in[1];
    const float* X      = (const float*)d_in[2];
    const float* We1    = (const float*)d_in[3];
    const float* be1    = (const float*)d_in[4];
    const float* We2    = (const float*)d_in[5];
    const float* be2    = (const float*)d_in[6];
    const float* v      = (const float*)d_in[7];
    float* out = (float*)d_out;

    char* ws = (char*)d_ws;
    _Float16* Af = (_Float16*)ws;                        // 512*512*2  = 524288 B
    float* g     = (float*)(ws + 524288);                // 128*512*4  = 262144 B
    float* E     = (float*)(ws + 524288 + 262144);       // 128*512*4  = 262144 B

    k_prep_a<<<16, 256, 0, stream>>>(We2, Af);
    k_hs<<<128, 256, 0, stream>>>(hidden, cell, We1, be1, be2, g);
    k_main<<<1024, 512, 0, stream>>>(X, Af, g, v, E);
    k_softmax<<<128, 256, 0, stream>>>(E, out);
}